// Round 1
// baseline (1458.516 us; speedup 1.0000x reference)
//
#include <hip/hip_runtime.h>
#include <stdint.h>

// Problem constants (B=4,S=2048,D=2048,E=8,H=2816,CAP_F=1.0)
#define T_TOK 8192
#define DDIM  2048
#define HDIM  2816
#define ENUM  8
#define CAPS  1024

typedef __attribute__((ext_vector_type(8))) __bf16 bf16x8;
typedef __attribute__((ext_vector_type(4))) float  floatx4;
typedef __attribute__((ext_vector_type(8))) unsigned short ushort8;

__device__ __forceinline__ unsigned short f2bf(float f) {
  union { float f; uint32_t u; } v; v.f = f;
  uint32_t r = v.u + 0x7fffu + ((v.u >> 16) & 1u);   // RNE
  return (unsigned short)(r >> 16);
}

// async global->LDS, 16B per lane. LDS dest must be wave-uniform base + lane*16.
__device__ __forceinline__ void async_copy16(const void* g, void* l) {
  __builtin_amdgcn_global_load_lds(
      (const __attribute__((address_space(1))) void*)(uintptr_t)g,
      (__attribute__((address_space(3))) void*)(uint32_t)(uintptr_t)l,
      16, 0, 0);
}

// ---------------- router: logits -> softmax -> argmax/gate (all fp32) -------
__global__ __launch_bounds__(256) void router_kernel(
    const float* __restrict__ x, const float* __restrict__ Wg,
    int* __restrict__ eidx, float* __restrict__ gate) {
  const int lane = threadIdx.x & 63;
  const int w    = threadIdx.x >> 6;
  const int t    = blockIdx.x * 4 + w;
  const float* xr = x + (size_t)t * DDIM;
  float acc[ENUM];
#pragma unroll
  for (int e = 0; e < ENUM; ++e) acc[e] = 0.f;
  for (int d = lane; d < DDIM; d += 64) {
    float xv = xr[d];
    const float* wr = Wg + d * ENUM;
#pragma unroll
    for (int e = 0; e < ENUM; ++e) acc[e] += xv * wr[e];
  }
#pragma unroll
  for (int off = 32; off > 0; off >>= 1)
#pragma unroll
    for (int e = 0; e < ENUM; ++e) acc[e] += __shfl_xor(acc[e], off);
  if (lane == 0) {
    float m = acc[0]; int am = 0;
#pragma unroll
    for (int e = 1; e < ENUM; ++e) if (acc[e] > m) { m = acc[e]; am = e; }  // first-max wins
    float s = 0.f;
#pragma unroll
    for (int e = 0; e < ENUM; ++e) s += expf(acc[e] - m);
    eidx[t] = am;
    gate[t] = 1.0f / s;   // prob of argmax expert
  }
}

// --------- ordered scan: per-expert positions, capacity, slot maps ----------
__global__ __launch_bounds__(256) void scan_kernel(
    const int* __restrict__ eidx, const float* __restrict__ gate,
    int* __restrict__ slot2tok, float* __restrict__ gatek) {
  __shared__ int eid_s[T_TOK];
  __shared__ int wcnt[4][ENUM];
  __shared__ int base[ENUM];
  const int tid = threadIdx.x, lane = tid & 63, w = tid >> 6;
  for (int i = tid; i < T_TOK; i += 256) { eid_s[i] = eidx[i]; slot2tok[i] = -1; }
  if (tid < ENUM) base[tid] = 0;
  __syncthreads();
  const unsigned long long below = (1ull << lane) - 1ull;
  for (int chunk = 0; chunk < T_TOK / 256; ++chunk) {
    const int t = chunk * 256 + tid;
    const int e = eid_s[t];
    int rank_w = 0;
#pragma unroll
    for (int e0 = 0; e0 < ENUM; ++e0) {
      unsigned long long m = __ballot(e == e0);
      if (e0 == e) rank_w = __popcll(m & below);
      if (lane == e0) wcnt[w][e0] = __popcll(m);
    }
    __syncthreads();
    int pos = base[e] + rank_w;
    for (int w2 = 0; w2 < w; ++w2) pos += wcnt[w2][e];
    const bool keep = pos < CAPS;
    if (keep) slot2tok[e * CAPS + pos] = t;
    gatek[t] = keep ? gate[t] : 0.f;
    __syncthreads();
    if (tid < ENUM) base[tid] += wcnt[0][tid] + wcnt[1][tid] + wcnt[2][tid] + wcnt[3][tid];
    __syncthreads();
  }
}

// ---------------- fp32 -> bf16 straight cast (x) ----------------------------
__global__ __launch_bounds__(256) void cast_bf16_kernel(
    const float* __restrict__ in, unsigned short* __restrict__ out) {
  const int i = blockIdx.x * 256 + threadIdx.x;   // 8 elems per thread
  const float4* in4 = (const float4*)in;
  float4 a = in4[(size_t)i * 2];
  float4 b = in4[(size_t)i * 2 + 1];
  ushort8 r;
  r[0] = f2bf(a.x); r[1] = f2bf(a.y); r[2] = f2bf(a.z); r[3] = f2bf(a.w);
  r[4] = f2bf(b.x); r[5] = f2bf(b.y); r[6] = f2bf(b.z); r[7] = f2bf(b.w);
  *(ushort8*)&out[(size_t)i * 8] = r;
}

// ---------------- fp32 [R,C] -> bf16 [C,R] transpose-cast -------------------
__global__ __launch_bounds__(256) void transpose_cast_kernel(
    const float* __restrict__ in, unsigned short* __restrict__ out, int R, int C) {
  __shared__ float tile[64][65];
  const int mat = blockIdx.z;
  in  += (size_t)mat * R * C;
  out += (size_t)mat * R * C;
  const int r0 = blockIdx.y * 64, c0 = blockIdx.x * 64;
  const int tr = threadIdx.x >> 6;   // 0..3
  const int tc = threadIdx.x & 63;
#pragma unroll
  for (int j = 0; j < 16; ++j) {
    int r = j * 4 + tr;
    tile[r][tc] = in[(size_t)(r0 + r) * C + c0 + tc];
  }
  __syncthreads();
#pragma unroll
  for (int j = 0; j < 16; ++j) {
    int c = j * 4 + tr;
    out[(size_t)(c0 + c) * R + r0 + tc] = f2bf(tile[tc][c]);
  }
}

// ------- GEMM1 fused dual-B: h = silu(A@W1^T)*(A@W3^T), tile 128x64(x2) -----
// A: bf16 [T,DDIM] (optionally row-gathered via slot2tok). B1,B3: bf16 [N=HDIM,K=DDIM] per expert.
template <bool GATHER>
__global__ __launch_bounds__(256, 2) void gemm13_kernel(
    const unsigned short* __restrict__ A, const int* __restrict__ s2t,
    const unsigned short* __restrict__ B1, const unsigned short* __restrict__ B3,
    unsigned short* __restrict__ Hout, int MperZ) {
  __shared__ unsigned short As [128 * 64];
  __shared__ unsigned short B1s[64 * 64];
  __shared__ unsigned short B3s[64 * 64];

  const int tid = threadIdx.x, lane = tid & 63, w = tid >> 6;
  const int wm = w >> 1, wn = w & 1;
  const int e  = blockIdx.z;
  const int n0 = blockIdx.x * 64;
  const int m0 = e * MperZ + blockIdx.y * 128;

  const size_t eoff = (size_t)e * HDIM * DDIM;
  const unsigned short* B1e = B1 + eoff;
  const unsigned short* B3e = B3 + eoff;

  const int rl = tid >> 3;          // 0..31 (staging row within chunk)
  const int kc = (tid & 7) * 8;     // staging k-offset (elems)

  const unsigned short* aptr[4];
#pragma unroll
  for (int c = 0; c < 4; ++c) {
    int row = m0 + c * 32 + rl;
    int ar;
    if (GATHER) { int t = s2t[row]; ar = (t < 0) ? 0 : t; }  // empty slot -> token 0, discarded later
    else ar = row;
    aptr[c] = A + (size_t)ar * DDIM + kc;
  }
  const unsigned short* bptr1[2];
  const unsigned short* bptr3[2];
#pragma unroll
  for (int c = 0; c < 2; ++c) {
    int row = n0 + c * 32 + rl;
    bptr1[c] = B1e + (size_t)row * DDIM + kc;
    bptr3[c] = B3e + (size_t)row * DDIM + kc;
  }
  unsigned short* lA  = &As [rl * 64 + kc];
  unsigned short* lB1 = &B1s[rl * 64 + kc];
  unsigned short* lB3 = &B3s[rl * 64 + kc];

  floatx4 acc1[4][2], acc3[4][2];
#pragma unroll
  for (int mf = 0; mf < 4; ++mf)
#pragma unroll
    for (int nf = 0; nf < 2; ++nf) {
      acc1[mf][nf] = (floatx4){0.f, 0.f, 0.f, 0.f};
      acc3[mf][nf] = (floatx4){0.f, 0.f, 0.f, 0.f};
    }
  const int quad = lane >> 4, l16 = lane & 15;

  for (int k0 = 0; k0 < DDIM; k0 += 64) {
    __syncthreads();
#pragma unroll
    for (int c = 0; c < 4; ++c) async_copy16(aptr[c] + k0, lA + c * 2048);
#pragma unroll
    for (int c = 0; c < 2; ++c) {
      async_copy16(bptr1[c] + k0, lB1 + c * 2048);
      async_copy16(bptr3[c] + k0, lB3 + c * 2048);
    }
    __syncthreads();
#pragma unroll
    for (int kk = 0; kk < 64; kk += 32) {
      bf16x8 af[4], b1f[2], b3f[2];
#pragma unroll
      for (int mf = 0; mf < 4; ++mf)
        af[mf] = *(const bf16x8*)&As[(wm * 64 + mf * 16 + l16) * 64 + kk + quad * 8];
#pragma unroll
      for (int nf = 0; nf < 2; ++nf) {
        b1f[nf] = *(const bf16x8*)&B1s[(wn * 32 + nf * 16 + l16) * 64 + kk + quad * 8];
        b3f[nf] = *(const bf16x8*)&B3s[(wn * 32 + nf * 16 + l16) * 64 + kk + quad * 8];
      }
#pragma unroll
      for (int mf = 0; mf < 4; ++mf)
#pragma unroll
        for (int nf = 0; nf < 2; ++nf) {
          acc1[mf][nf] = __builtin_amdgcn_mfma_f32_16x16x32_bf16(af[mf], b1f[nf], acc1[mf][nf], 0, 0, 0);
          acc3[mf][nf] = __builtin_amdgcn_mfma_f32_16x16x32_bf16(af[mf], b3f[nf], acc3[mf][nf], 0, 0, 0);
        }
    }
  }
  // epilogue: SwiGLU -> bf16 h. C/D layout: col=lane&15, row=quad*4+reg (m89/m91-verified)
#pragma unroll
  for (int mf = 0; mf < 4; ++mf)
#pragma unroll
    for (int nf = 0; nf < 2; ++nf)
#pragma unroll
      for (int r = 0; r < 4; ++r) {
        int m = m0 + wm * 64 + mf * 16 + quad * 4 + r;
        int n = n0 + wn * 32 + nf * 16 + l16;
        float v1 = acc1[mf][nf][r], v3 = acc3[mf][nf][r];
        float hv = (v1 / (1.f + __expf(-v1))) * v3;
        Hout[(size_t)m * HDIM + n] = f2bf(hv);
      }
}

// ------- GEMM2: oe = h @ W2^T, tile 128x128. EPI 0: scatter gate*oe -> out[tok].
//         EPI 1: out[tok] += oe (shared expert). -----------------------------
template <int EPI>
__global__ __launch_bounds__(256, 2) void gemm2_kernel(
    const unsigned short* __restrict__ Hb, const unsigned short* __restrict__ B2,
    const int* __restrict__ s2t, const float* __restrict__ gk,
    float* __restrict__ Out, int MperZ) {
  __shared__ unsigned short As[128 * 64];
  __shared__ unsigned short Bs[128 * 64];
  __shared__ int toks[128];

  const int tid = threadIdx.x, lane = tid & 63, w = tid >> 6;
  const int wm = w >> 1, wn = w & 1;
  const int e  = blockIdx.z;
  const int n0 = blockIdx.x * 128;
  const int m0 = e * MperZ + blockIdx.y * 128;

  const unsigned short* B2e = B2 + (size_t)e * DDIM * HDIM;
  if (EPI == 0) { if (tid < 128) toks[tid] = s2t[m0 + tid]; }

  const int rl = tid >> 3;
  const int kc = (tid & 7) * 8;

  const unsigned short* aptr[4];
  const unsigned short* bptr[4];
#pragma unroll
  for (int c = 0; c < 4; ++c) {
    aptr[c] = Hb  + (size_t)(m0 + c * 32 + rl) * HDIM + kc;
    bptr[c] = B2e + (size_t)(n0 + c * 32 + rl) * HDIM + kc;
  }
  unsigned short* lA = &As[rl * 64 + kc];
  unsigned short* lB = &Bs[rl * 64 + kc];

  floatx4 acc[4][4];
#pragma unroll
  for (int mf = 0; mf < 4; ++mf)
#pragma unroll
    for (int nf = 0; nf < 4; ++nf) acc[mf][nf] = (floatx4){0.f, 0.f, 0.f, 0.f};
  const int quad = lane >> 4, l16 = lane & 15;

  for (int k0 = 0; k0 < HDIM; k0 += 64) {
    __syncthreads();
#pragma unroll
    for (int c = 0; c < 4; ++c) {
      async_copy16(aptr[c] + k0, lA + c * 2048);
      async_copy16(bptr[c] + k0, lB + c * 2048);
    }
    __syncthreads();
#pragma unroll
    for (int kk = 0; kk < 64; kk += 32) {
      bf16x8 af[4], bf[4];
#pragma unroll
      for (int mf = 0; mf < 4; ++mf)
        af[mf] = *(const bf16x8*)&As[(wm * 64 + mf * 16 + l16) * 64 + kk + quad * 8];
#pragma unroll
      for (int nf = 0; nf < 4; ++nf)
        bf[nf] = *(const bf16x8*)&Bs[(wn * 64 + nf * 16 + l16) * 64 + kk + quad * 8];
#pragma unroll
      for (int mf = 0; mf < 4; ++mf)
#pragma unroll
        for (int nf = 0; nf < 4; ++nf)
          acc[mf][nf] = __builtin_amdgcn_mfma_f32_16x16x32_bf16(af[mf], bf[nf], acc[mf][nf], 0, 0, 0);
    }
  }
#pragma unroll
  for (int mf = 0; mf < 4; ++mf)
#pragma unroll
    for (int nf = 0; nf < 4; ++nf)
#pragma unroll
      for (int r = 0; r < 4; ++r) {
        int ml = wm * 64 + mf * 16 + quad * 4 + r;
        int n  = n0 + wn * 64 + nf * 16 + l16;
        float v = acc[mf][nf][r];
        if (EPI == 0) {
          int t = toks[ml];
          if (t >= 0) Out[(size_t)t * DDIM + n] = gk[t] * v;
        } else {
          size_t o = (size_t)(m0 + ml) * DDIM + n;
          Out[o] += v;
        }
      }
}

// ---------------------------------------------------------------------------
extern "C" void kernel_launch(void* const* d_in, const int* in_sizes, int n_in,
                              void* d_out, int out_size, void* d_ws, size_t ws_size,
                              hipStream_t stream) {
  const float* x   = (const float*)d_in[0];
  const float* Wg  = (const float*)d_in[1];
  const float* W1  = (const float*)d_in[2];
  const float* W3  = (const float*)d_in[3];
  const float* W2  = (const float*)d_in[4];
  const float* sw1 = (const float*)d_in[5];
  const float* sw3 = (const float*)d_in[6];
  const float* sw2 = (const float*)d_in[7];
  float* out = (float*)d_out;

  char* ws = (char*)d_ws;
  size_t off = 0;
  auto alloc = [&](size_t bytes) -> void* {
    void* p = ws + off;
    off = (off + bytes + 255) & ~(size_t)255;
    return p;
  };
  int*   eidx     = (int*)alloc((size_t)T_TOK * 4);
  float* gate     = (float*)alloc((size_t)T_TOK * 4);
  int*   slot2tok = (int*)alloc((size_t)T_TOK * 4);
  float* gatek    = (float*)alloc((size_t)T_TOK * 4);
  unsigned short* xbf  = (unsigned short*)alloc((size_t)T_TOK * DDIM * 2);
  unsigned short* W1t  = (unsigned short*)alloc((size_t)ENUM * HDIM * DDIM * 2);
  unsigned short* W3t  = (unsigned short*)alloc((size_t)ENUM * HDIM * DDIM * 2);
  unsigned short* W2t  = (unsigned short*)alloc((size_t)ENUM * DDIM * HDIM * 2);
  unsigned short* s1t  = (unsigned short*)alloc((size_t)HDIM * DDIM * 2);
  unsigned short* s3t  = (unsigned short*)alloc((size_t)HDIM * DDIM * 2);
  unsigned short* s2t  = (unsigned short*)alloc((size_t)DDIM * HDIM * 2);
  unsigned short* hexp = (unsigned short*)alloc((size_t)T_TOK * HDIM * 2);
  unsigned short* hsh  = (unsigned short*)alloc((size_t)T_TOK * HDIM * 2);
  if (off > ws_size) {  // workspace too small: emit zeros so the failure is identifiable
    hipMemsetAsync(d_out, 0, (size_t)out_size * 4, stream);
    return;
  }

  router_kernel<<<T_TOK / 4, 256, 0, stream>>>(x, Wg, eidx, gate);
  scan_kernel<<<1, 256, 0, stream>>>(eidx, gate, slot2tok, gatek);
  cast_bf16_kernel<<<(T_TOK * (DDIM / 8)) / 256, 256, 0, stream>>>(x, xbf);
  transpose_cast_kernel<<<dim3(HDIM / 64, DDIM / 64, ENUM), 256, 0, stream>>>(W1, W1t, DDIM, HDIM);
  transpose_cast_kernel<<<dim3(HDIM / 64, DDIM / 64, ENUM), 256, 0, stream>>>(W3, W3t, DDIM, HDIM);
  transpose_cast_kernel<<<dim3(DDIM / 64, HDIM / 64, ENUM), 256, 0, stream>>>(W2, W2t, HDIM, DDIM);
  transpose_cast_kernel<<<dim3(HDIM / 64, DDIM / 64, 1), 256, 0, stream>>>(sw1, s1t, DDIM, HDIM);
  transpose_cast_kernel<<<dim3(HDIM / 64, DDIM / 64, 1), 256, 0, stream>>>(sw3, s3t, DDIM, HDIM);
  transpose_cast_kernel<<<dim3(DDIM / 64, HDIM / 64, 1), 256, 0, stream>>>(sw2, s2t, HDIM, DDIM);

  gemm13_kernel<true><<<dim3(HDIM / 64, CAPS / 128, ENUM), 256, 0, stream>>>(
      xbf, slot2tok, W1t, W3t, hexp, CAPS);
  gemm13_kernel<false><<<dim3(HDIM / 64, T_TOK / 128, 1), 256, 0, stream>>>(
      xbf, nullptr, s1t, s3t, hsh, T_TOK);

  hipMemsetAsync(d_out, 0, (size_t)T_TOK * DDIM * 4, stream);
  gemm2_kernel<0><<<dim3(DDIM / 128, CAPS / 128, ENUM), 256, 0, stream>>>(
      hexp, W2t, slot2tok, gatek, out, CAPS);
  gemm2_kernel<1><<<dim3(DDIM / 128, T_TOK / 128, 1), 256, 0, stream>>>(
      hsh, s2t, nullptr, nullptr, out, T_TOK);
}